// Round 4
// baseline (1403.686 us; speedup 1.0000x reference)
//
#include <hip/hip_runtime.h>
#include <hip/hip_fp16.h>

#define BB 16
#define TT 4096
#define TSZ 64
#define DE 128
#define HH 256
#define LDIM 512
#define ODIM 10
#define NBLKS 6
#define EPSF 1e-5f
#define NC32 128          // 32-token chunks (scan/carry granularity)
#define NC64 64           // 64-token tiles for k_A
#define NROWS (BB*TT)     // 65536

typedef _Float16 f16x8 __attribute__((ext_vector_type(8)));
typedef _Float16 f16x4 __attribute__((ext_vector_type(4)));
typedef float f32x4 __attribute__((ext_vector_type(4)));
#define MFMA16(a,b,c) __builtin_amdgcn_mfma_f32_16x16x32_f16((a),(b),(c),0,0,0)

// ---- f16 weight region layout (offsets in halfs, base = ws + WOFF_W16) ----
enum : size_t {
  HOFF_BG = 0,                                  // [NBLK][512][128]  gamma*B rows (re|im)
  HOFF_WC = HOFF_BG + (size_t)NBLKS*512*128,    // [NBLK][128][512]  C-proj [d][hc]
  HOFF_W1 = HOFF_WC + (size_t)NBLKS*128*512,    // [NBLK][512][128]  W1^T [l][d]
  HOFF_W2 = HOFF_W1 + (size_t)NBLKS*512*128,    // [NBLK][128][256]  W2^T [d][g]
  HOFF_WE = HOFF_W2 + (size_t)NBLKS*128*256,    // [128][64]         Wenc^T
  HTOT_HALFS = HOFF_WE + 128*64
};

// ---- workspace layout (float offsets) ----
enum : size_t {
  WOFF_Y     = 0,                                    // __half [NROWS*DE] encoder out
  WOFF_H     = WOFF_Y + (size_t)NROWS*DE/2,          // __half [NROWS*DE] running hidden
  WOFF_W16   = WOFF_H + (size_t)NROWS*DE/2,          // f16 weights
  WOFF_LAM   = WOFF_W16 + (HTOT_HALFS+1)/2,          // [NBLK][256][2] f32
  WOFF_PL    = WOFF_LAM + (size_t)NBLKS*HH*2,        // [NBLK][128][256][2] (lam^32)^k
  WOFF_SL    = WOFF_PL + (size_t)NBLKS*NC32*HH*2,    // [B][128][256][2] chunk states
  WOFF_STATS = WOFF_SL + (size_t)BB*NC32*HH*2,       // [NBLK+1][2][128]
  WOFF_POOL  = WOFF_STATS + (size_t)(NBLKS+1)*2*DE,  // [B][128]
  WOFF_BU    = WOFF_POOL + (size_t)BB*DE,            // __half [B][128][512][32]
  WS_FLOATS  = WOFF_BU + (size_t)BB*NC32*512*32/2
};

// ============================ prep ============================
__global__ __launch_bounds__(256) void k_prep(
    const float* __restrict__ nu_log, const float* __restrict__ theta_log,
    const float* __restrict__ B_re, const float* __restrict__ B_im,
    const float* __restrict__ C_re, const float* __restrict__ C_im,
    const float* __restrict__ W1g, const float* __restrict__ W2g,
    const float* __restrict__ Wenc, float* __restrict__ ws)
{
  const int i = blockIdx.x, h = threadIdx.x;
  __half* w16 = (__half*)(ws + WOFF_W16);
  const float nu  = expf(nu_log[i*HH+h]);
  const float th  = expf(theta_log[i*HH+h]);
  const float mod = expf(-nu);
  const float lr = mod*cosf(th), li = mod*sinf(th);
  const float gamma = sqrtf(fmaxf(1.0f - mod*mod, 1e-8f));
  ws[WOFF_LAM + ((size_t)i*HH+h)*2+0] = lr;
  ws[WOFF_LAM + ((size_t)i*HH+h)*2+1] = li;
  // lamL = lam^32 (5 squarings), then PL[k] = lamL^k for k=0..127
  {
    float ar = lr, ai = li;
    #pragma unroll
    for (int q = 0; q < 5; q++) { float nr=ar*ar-ai*ai, ni=2.0f*ar*ai; ar=nr; ai=ni; }
    float pr = 1.0f, pi = 0.0f;
    float* PL = ws + WOFF_PL + (size_t)i*NC32*HH*2;
    for (int k = 0; k < NC32; k++) {
      PL[((size_t)k*HH + h)*2+0] = pr;
      PL[((size_t)k*HH + h)*2+1] = pi;
      const float nr = pr*ar - pi*ai, ni = pr*ai + pi*ar;
      pr = nr; pi = ni;
    }
  }
  // BG [512][128]
  {
    __half* bg = w16 + HOFF_BG + (size_t)i*512*128;
    const float* bre = B_re + ((size_t)i*HH+h)*DE;
    const float* bim = B_im + ((size_t)i*HH+h)*DE;
    for (int d = 0; d < DE; d++) {
      bg[(size_t)h*128 + d]       = __float2half(bre[d]*gamma);
      bg[(size_t)(256+h)*128 + d] = __float2half(bim[d]*gamma);
    }
  }
  // WC [128][512]
  {
    __half* wc = w16 + HOFF_WC + (size_t)i*128*512;
    const float* cre = C_re + (size_t)i*DE*HH;
    const float* cim = C_im + (size_t)i*DE*HH;
    for (int d = 0; d < DE; d++) {
      wc[(size_t)d*512 + h]       = __float2half( cre[(size_t)d*HH + h]);
      wc[(size_t)d*512 + 256 + h] = __float2half(-cim[(size_t)d*HH + h]);
    }
  }
  // W1T [512][128]
  {
    __half* w1t = w16 + HOFF_W1 + (size_t)i*512*128;
    for (int d = 0; d < DE; d++) {
      w1t[(size_t)h*128 + d]       = __float2half(W1g[((size_t)i*DE + d)*LDIM + h]);
      w1t[(size_t)(256+h)*128 + d] = __float2half(W1g[((size_t)i*DE + d)*LDIM + 256 + h]);
    }
  }
  // W2T [128][256]
  if (h < 128) {
    __half* w2t = w16 + HOFF_W2 + (size_t)i*128*256;
    for (int g = 0; g < 256; g++)
      w2t[(size_t)h*256 + g] = __float2half(W2g[((size_t)i*256 + g)*DE + h]);
  }
  // WencT [128][64]
  if (i == 0 && h < 128) {
    __half* wet = w16 + HOFF_WE;
    for (int k = 0; k < TSZ; k++)
      wet[(size_t)h*TSZ + k] = __float2half(Wenc[(size_t)k*DE + h]);
  }
}

// ============================ encoder ============================
__global__ __launch_bounds__(512) void k_enc(
    const float* __restrict__ x, const float* __restrict__ benc, float* __restrict__ ws)
{
  __shared__ __half XT[64*72];
  const int tid = threadIdx.x, w = tid >> 6, l = tid & 63;
  const size_t row0 = (size_t)blockIdx.x * 64;
  {
    const float4* xg = (const float4*)(x + row0*TSZ);
    for (int idx = tid; idx < 1024; idx += 512) {
      float4 v = xg[idx];
      const int r = idx >> 4, c4 = (idx & 15)*4;
      *(__half2*)&XT[r*72 + c4]     = __half2{__float2half(v.x), __float2half(v.y)};
      *(__half2*)&XT[r*72 + c4 + 2] = __half2{__float2half(v.z), __float2half(v.w)};
    }
  }
  __syncthreads();
  const __half* wet = (const __half*)(ws + WOFF_W16) + HOFF_WE;
  const int n0 = w*16;
  f32x4 acc[4];
  #pragma unroll
  for (int mt = 0; mt < 4; mt++) acc[mt] = (f32x4)(0.0f);
  #pragma unroll
  for (int k0 = 0; k0 < 64; k0 += 32) {
    f16x8 bf = *(const f16x8*)&wet[(size_t)(n0 + (l&15))*64 + k0 + (l>>4)*8];
    #pragma unroll
    for (int mt = 0; mt < 4; mt++) {
      f16x8 af = *(const f16x8*)&XT[(mt*16 + (l&15))*72 + k0 + (l>>4)*8];
      acc[mt] = MFMA16(af, bf, acc[mt]);
    }
  }
  const int d = n0 + (l&15);
  const float be = benc[d];
  float s = 0.0f, ss = 0.0f;
  __half* y = (__half*)(ws + WOFF_Y);
  #pragma unroll
  for (int mt = 0; mt < 4; mt++)
    #pragma unroll
    for (int j = 0; j < 4; j++) {
      const int t = mt*16 + (l>>4)*4 + j;
      const float v = acc[mt][j] + be;
      y[(row0 + t)*DE + d] = __float2half(v);
      s += v; ss += v*v;
    }
  s  += __shfl_xor(s, 16);  s  += __shfl_xor(s, 32);
  ss += __shfl_xor(ss, 16); ss += __shfl_xor(ss, 32);
  if (l < 16) {
    atomicAdd(ws + WOFF_STATS + d, s);
    atomicAdd(ws + WOFF_STATS + DE + d, ss);
  }
}

// ============================ k_A: BN + B-proj -> Bu ============================
__global__ __launch_bounds__(512, 4) void k_A(
    const __half* __restrict__ hin, float* __restrict__ ws,
    const float* __restrict__ bnsg, const float* __restrict__ bnbg, int iblk)
{
  __shared__ float AC[256];
  __shared__ __half U[64*136];
  const int tid = threadIdx.x, w = tid >> 6, l = tid & 63, q = l >> 4, r = l & 15;
  const int b = blockIdx.y, cb = blockIdx.x;
  const int row0 = b*TT + cb*64;
  if (tid < 128) {
    const float inv = 1.0f / (float)NROWS;
    const float s  = ws[WOFF_STATS + ((size_t)iblk*2+0)*DE + tid];
    const float sq = ws[WOFF_STATS + ((size_t)iblk*2+1)*DE + tid];
    const float mean = s*inv;
    const float var  = sq*inv - mean*mean;
    const float a = rsqrtf(var + EPSF) * bnsg[iblk*DE + tid];
    AC[tid]       = a;
    AC[128 + tid] = bnbg[iblk*DE + tid] - mean*a;
  }
  __syncthreads();
  // BN -> U
  {
    const int row = tid >> 3, d0 = (tid & 7)*16;
    const f16x8* hp = (const f16x8*)(hin + (size_t)(row0+row)*DE + d0);
    f16x8 h0 = hp[0], h1 = hp[1];
    f16x8 u0, u1;
    #pragma unroll
    for (int j = 0; j < 8; j++) {
      u0[j] = (_Float16)((float)h0[j]*AC[d0+j]   + AC[128+d0+j]);
      u1[j] = (_Float16)((float)h1[j]*AC[d0+8+j] + AC[128+d0+8+j]);
    }
    *(f16x8*)&U[row*136 + d0]     = u0;
    *(f16x8*)&U[row*136 + d0 + 8] = u1;
  }
  __syncthreads();
  // B-proj: M=64, N=512, K=128; wave N=64
  const __half* BG = (const __half*)(ws + WOFF_W16) + HOFF_BG + (size_t)iblk*512*128;
  const int n0 = w*64;
  f32x4 acc[4][4];
  #pragma unroll
  for (int mt = 0; mt < 4; mt++)
    #pragma unroll
    for (int nt = 0; nt < 4; nt++) acc[mt][nt] = (f32x4)(0.0f);
  #pragma unroll
  for (int k0 = 0; k0 < 128; k0 += 32) {
    f16x8 af[4], bf[4];
    #pragma unroll
    for (int mt = 0; mt < 4; mt++)
      af[mt] = *(const f16x8*)&U[(mt*16 + r)*136 + k0 + q*8];
    #pragma unroll
    for (int nt = 0; nt < 4; nt++)
      bf[nt] = *(const f16x8*)&BG[(size_t)(n0 + nt*16 + r)*128 + k0 + q*8];
    #pragma unroll
    for (int mt = 0; mt < 4; mt++)
      #pragma unroll
      for (int nt = 0; nt < 4; nt++)
        acc[mt][nt] = MFMA16(af[mt], bf[nt], acc[mt][nt]);
  }
  // write Bu [b][c32][hc][t32] f16, packed 4 t per store
  __half* bu = (__half*)(ws + WOFF_BU);
  #pragma unroll
  for (int mt = 0; mt < 4; mt++)
    #pragma unroll
    for (int nt = 0; nt < 4; nt++) {
      f16x4 pk;
      pk[0] = (_Float16)acc[mt][nt][0];
      pk[1] = (_Float16)acc[mt][nt][1];
      pk[2] = (_Float16)acc[mt][nt][2];
      pk[3] = (_Float16)acc[mt][nt][3];
      const int hc = n0 + nt*16 + r;
      __half* dst = bu + ((((size_t)b*NC32 + cb*2 + (mt>>1))*512 + hc)*32 + (mt&1)*16 + q*4);
      *(f16x4*)dst = pk;
    }
}

// ============================ k_pre: local scans -> SL ============================
__global__ __launch_bounds__(256) void k_pre(float* __restrict__ ws, int iblk)
{
  const int h = threadIdx.x, c = blockIdx.x, b = blockIdx.y;
  const __half* bu = (const __half*)(ws + WOFF_BU) + ((size_t)(b*NC32 + c)*512)*32;
  f16x8 re[4], im[4];
  #pragma unroll
  for (int k = 0; k < 4; k++) {
    re[k] = *(const f16x8*)(bu + (size_t)h*32 + k*8);
    im[k] = *(const f16x8*)(bu + (size_t)(256+h)*32 + k*8);
  }
  const float lr = ws[WOFF_LAM + ((size_t)iblk*HH+h)*2+0];
  const float li = ws[WOFF_LAM + ((size_t)iblk*HH+h)*2+1];
  float sr = 0.0f, si = 0.0f;
  #pragma unroll
  for (int t = 0; t < 32; t++) {
    const float br = (float)re[t>>3][t&7];
    const float bi = (float)im[t>>3][t&7];
    const float nr = lr*sr - li*si + br;
    const float ni = lr*si + li*sr + bi;
    sr = nr; si = ni;
  }
  ws[WOFF_SL + ((size_t)(b*NC32+c)*HH + h)*2+0] = sr;
  ws[WOFF_SL + ((size_t)(b*NC32+c)*HH + h)*2+1] = si;
}

// ============================ k_BC: carry + scan + C-proj + MLP ============================
__global__ __launch_bounds__(512, 4) void k_BC(
    const __half* __restrict__ hin, float* __restrict__ ws,
    const float* __restrict__ bnsg, const float* __restrict__ bnbg,
    const float* __restrict__ b1g, const float* __restrict__ b2g,
    const float* __restrict__ Dvg, int iblk, int islast)
{
  __shared__ __half HT[32*520];   // scan h -> Z1 -> G (in place)
  __shared__ __half YL[32*136];
  __shared__ float AC[256];
  __shared__ float DVs[128];
  const int tid = threadIdx.x, w = tid >> 6, l = tid & 63, q = l >> 4, r = l & 15;
  const int b = blockIdx.y, cb = blockIdx.x;
  const int row0 = b*TT + cb*32;
  const __half* w16 = (const __half*)(ws + WOFF_W16);

  if (tid < 128) {
    const float inv = 1.0f / (float)NROWS;
    const float s  = ws[WOFF_STATS + ((size_t)iblk*2+0)*DE + tid];
    const float sq = ws[WOFF_STATS + ((size_t)iblk*2+1)*DE + tid];
    const float mean = s*inv;
    const float var  = sq*inv - mean*mean;
    const float a = rsqrtf(var + EPSF) * bnsg[iblk*DE + tid];
    AC[tid]       = a;
    AC[128 + tid] = bnbg[iblk*DE + tid] - mean*a;
    DVs[tid] = Dvg[iblk*DE + tid];
  }
  // S1: carry (weighted SL sum) + register scan -> HT
  if (tid < HH) {
    const int h = tid;
    float cr = 0.0f, ci = 0.0f;
    const float2* PLp = (const float2*)(ws + WOFF_PL) + (size_t)iblk*NC32*HH + h;
    const float2* SLp = (const float2*)(ws + WOFF_SL) + (size_t)b*NC32*HH + h;
    for (int k = 0; k < cb; k++) {
      const float2 p  = PLp[(size_t)k*HH];
      const float2 sv = SLp[(size_t)(cb-1-k)*HH];
      cr += p.x*sv.x - p.y*sv.y;
      ci += p.x*sv.y + p.y*sv.x;
    }
    const __half* bu = (const __half*)(ws + WOFF_BU) + ((size_t)(b*NC32 + cb)*512)*32;
    f16x8 re[4], im[4];
    #pragma unroll
    for (int k = 0; k < 4; k++) {
      re[k] = *(const f16x8*)(bu + (size_t)h*32 + k*8);
      im[k] = *(const f16x8*)(bu + (size_t)(256+h)*32 + k*8);
    }
    const float lr = ws[WOFF_LAM + ((size_t)iblk*HH+h)*2+0];
    const float li = ws[WOFF_LAM + ((size_t)iblk*HH+h)*2+1];
    float sr = cr, si = ci;
    #pragma unroll
    for (int t = 0; t < 32; t++) {
      const float br = (float)re[t>>3][t&7];
      const float bi = (float)im[t>>3][t&7];
      const float nr = lr*sr - li*si + br;
      const float ni = lr*si + li*sr + bi;
      sr = nr; si = ni;
      HT[t*520 + h]       = __float2half(sr);
      HT[t*520 + 256 + h] = __float2half(si);
    }
  }
  __syncthreads();
  // S2: C-proj ylru = Re(C h) + u*D  (M=32,N=128,K=512); wave N=16
  {
    const __half* WC = w16 + HOFF_WC + (size_t)iblk*128*512;
    const int d = w*16 + r;
    f32x4 a0 = (f32x4)(0.0f), a1 = (f32x4)(0.0f);
    #pragma unroll
    for (int k0 = 0; k0 < 512; k0 += 32) {
      f16x8 bf  = *(const f16x8*)&WC[(size_t)d*512 + k0 + q*8];
      f16x8 af0 = *(const f16x8*)&HT[(r)*520      + k0 + q*8];
      f16x8 af1 = *(const f16x8*)&HT[(16 + r)*520 + k0 + q*8];
      a0 = MFMA16(af0, bf, a0);
      a1 = MFMA16(af1, bf, a1);
    }
    const float dv = DVs[d], a = AC[d], c = AC[128+d];
    #pragma unroll
    for (int mt = 0; mt < 2; mt++)
      #pragma unroll
      for (int j = 0; j < 4; j++) {
        const int t = mt*16 + q*4 + j;
        const float u = (float)hin[(size_t)(row0+t)*DE + d]*a + c;
        const float v = (mt ? a1[j] : a0[j]) + u*dv;
        YL[t*136 + d] = __float2half(v);
      }
  }
  __syncthreads();
  // S3: Z1 = YL @ W1 + b1 -> HT  (M=32,N=512,K=128); wave N=64, two N=32 passes
  {
    const __half* W1T = w16 + HOFF_W1 + (size_t)iblk*512*128;
    #pragma unroll
    for (int p = 0; p < 2; p++) {
      const int n0 = w*64 + p*32;
      f32x4 acc[2][2];
      #pragma unroll
      for (int mt = 0; mt < 2; mt++)
        #pragma unroll
        for (int nt = 0; nt < 2; nt++) acc[mt][nt] = (f32x4)(0.0f);
      #pragma unroll
      for (int k0 = 0; k0 < 128; k0 += 32) {
        f16x8 af[2], bf[2];
        #pragma unroll
        for (int mt = 0; mt < 2; mt++)
          af[mt] = *(const f16x8*)&YL[(mt*16 + r)*136 + k0 + q*8];
        #pragma unroll
        for (int nt = 0; nt < 2; nt++)
          bf[nt] = *(const f16x8*)&W1T[(size_t)(n0 + nt*16 + r)*128 + k0 + q*8];
        #pragma unroll
        for (int mt = 0; mt < 2; mt++)
          #pragma unroll
          for (int nt = 0; nt < 2; nt++)
            acc[mt][nt] = MFMA16(af[mt], bf[nt], acc[mt][nt]);
      }
      #pragma unroll
      for (int nt = 0; nt < 2; nt++) {
        const int col = n0 + nt*16 + r;
        const float bb = b1g[(size_t)iblk*LDIM + col];
        #pragma unroll
        for (int mt = 0; mt < 2; mt++)
          #pragma unroll
          for (int j = 0; j < 4; j++)
            HT[(mt*16 + q*4 + j)*520 + col] = __float2half(acc[mt][nt][j] + bb);
      }
    }
  }
  __syncthreads();
  // S4: GLU in place: HT[t][j] = HT[t][j] * sigmoid(HT[t][j+256]), j<256
  #pragma unroll
  for (int it = 0; it < 16; it++) {
    const int idx = tid + it*512;
    const int t = idx >> 8, j = idx & 255;
    const float av = (float)HT[t*520 + j];
    const float bv = (float)HT[t*520 + 256 + j];
    HT[t*520 + j] = __float2half(av / (1.0f + __expf(-bv)));
  }
  __syncthreads();
  // S5: h_new = G @ W2 + b2 + y  (M=32,N=128,K=256); wave N=16
  {
    const __half* W2T = w16 + HOFF_W2 + (size_t)iblk*128*256;
    const int d = w*16 + r;
    f32x4 a0 = (f32x4)(0.0f), a1 = (f32x4)(0.0f);
    #pragma unroll
    for (int k0 = 0; k0 < 256; k0 += 32) {
      f16x8 bf  = *(const f16x8*)&W2T[(size_t)d*256 + k0 + q*8];
      f16x8 af0 = *(const f16x8*)&HT[(r)*520      + k0 + q*8];
      f16x8 af1 = *(const f16x8*)&HT[(16 + r)*520 + k0 + q*8];
      a0 = MFMA16(af0, bf, a0);
      a1 = MFMA16(af1, bf, a1);
    }
    const __half* yh = (const __half*)(ws + WOFF_Y);
    __half* hh = (__half*)(ws + WOFF_H);
    const float bb = b2g[(size_t)iblk*DE + d];
    float s = 0.0f, ss = 0.0f;
    #pragma unroll
    for (int mt = 0; mt < 2; mt++)
      #pragma unroll
      for (int j = 0; j < 4; j++) {
        const int t = mt*16 + q*4 + j;
        const size_t row = (size_t)(row0 + t);
        const float v = (mt ? a1[j] : a0[j]) + bb + (float)yh[row*DE + d];
        hh[row*DE + d] = __float2half(v);
        s += v; ss += v*v;
      }
    s  += __shfl_xor(s, 16);  s  += __shfl_xor(s, 32);
    ss += __shfl_xor(ss, 16); ss += __shfl_xor(ss, 32);
    if (l < 16) {
      atomicAdd(ws + WOFF_STATS + (size_t)((iblk+1)*2 + 0)*DE + d, s);
      atomicAdd(ws + WOFF_STATS + (size_t)((iblk+1)*2 + 1)*DE + d, ss);
      if (islast) atomicAdd(ws + WOFF_POOL + (size_t)b*DE + d, s);
    }
  }
}

// ============================ final projection ============================
__global__ void k_out(const float* __restrict__ Wout, const float* __restrict__ bout,
                      const float* __restrict__ ws, float* __restrict__ out)
{
  const int tid = threadIdx.x;
  if (tid < BB*ODIM) {
    const int b = tid / ODIM, o = tid % ODIM;
    float acc = bout[o];
    const float* p = ws + WOFF_POOL + (size_t)b*DE;
    const float invT = 1.0f / (float)TT;
    for (int d = 0; d < DE; d++) acc += p[d]*invT*Wout[d*ODIM + o];
    out[tid] = acc;
  }
}

extern "C" void kernel_launch(void* const* d_in, const int* in_sizes, int n_in,
                              void* d_out, int out_size, void* d_ws, size_t ws_size,
                              hipStream_t stream)
{
  const float* x   = (const float*)d_in[0];
  const float* nu  = (const float*)d_in[1];
  const float* th  = (const float*)d_in[2];
  const float* Bre = (const float*)d_in[3];
  const float* Bim = (const float*)d_in[4];
  const float* Cre = (const float*)d_in[5];
  const float* Cim = (const float*)d_in[6];
  const float* Dv  = (const float*)d_in[7];
  const float* W1  = (const float*)d_in[8];
  const float* b1  = (const float*)d_in[9];
  const float* W2  = (const float*)d_in[10];
  const float* b2  = (const float*)d_in[11];
  const float* bns = (const float*)d_in[12];
  const float* bnb = (const float*)d_in[13];
  const float* We  = (const float*)d_in[14];
  const float* be  = (const float*)d_in[15];
  const float* Wo  = (const float*)d_in[16];
  const float* bo  = (const float*)d_in[17];
  float* ws = (float*)d_ws;
  float* out = (float*)d_out;

  hipMemsetAsync(ws + WOFF_STATS, 0,
                 (size_t)(((NBLKS+1)*2*DE) + BB*DE)*sizeof(float), stream);

  k_prep<<<NBLKS, 256, 0, stream>>>(nu, th, Bre, Bim, Cre, Cim, W1, W2, We, ws);
  k_enc<<<NROWS/64, 512, 0, stream>>>(x, be, ws);

  const __half* Yh = (const __half*)(ws + WOFF_Y);
  const __half* Hh = (const __half*)(ws + WOFF_H);
  for (int i = 0; i < NBLKS; i++) {
    const __half* hin = (i == 0) ? Yh : Hh;
    k_A  <<<dim3(NC64, BB), 512, 0, stream>>>(hin, ws, bns, bnb, i);
    k_pre<<<dim3(NC32, BB), 256, 0, stream>>>(ws, i);
    k_BC <<<dim3(NC32, BB), 512, 0, stream>>>(hin, ws, bns, bnb, b1, b2, Dv, i,
                                              (i == NBLKS-1) ? 1 : 0);
  }
  k_out<<<1, 256, 0, stream>>>(Wo, bo, ws, out);
}

// Round 5
// 958.802 us; speedup vs baseline: 1.4640x; 1.4640x over previous
//
#include <hip/hip_runtime.h>
#include <hip/hip_fp16.h>

#define BB 16
#define TT 4096
#define TSZ 64
#define DE 128
#define HH 256
#define LDIM 512
#define ODIM 10
#define NBLKS 6
#define EPSF 1e-5f
#define NC32 128          // 32-token chunks (scan/carry granularity)
#define NC64 64           // 64-token tiles (k_A, k_BC)
#define NROWS (BB*TT)     // 65536

typedef _Float16 f16x8 __attribute__((ext_vector_type(8)));
typedef _Float16 f16x4 __attribute__((ext_vector_type(4)));
typedef float f32x4 __attribute__((ext_vector_type(4)));
#define MFMA16(a,b,c) __builtin_amdgcn_mfma_f32_16x16x32_f16((a),(b),(c),0,0,0)

// ---- f16 weight region layout (offsets in halfs, base = ws + WOFF_W16) ----
enum : size_t {
  HOFF_BG = 0,                                  // [NBLK][512][128]  gamma*B rows (re|im)
  HOFF_WC = HOFF_BG + (size_t)NBLKS*512*128,    // [NBLK][128][512]  C-proj [d][hc]
  HOFF_W1 = HOFF_WC + (size_t)NBLKS*128*512,    // [NBLK][512][128]  W1^T [l][d]
  HOFF_W2 = HOFF_W1 + (size_t)NBLKS*512*128,    // [NBLK][128][256]  W2^T [d][g]
  HOFF_WE = HOFF_W2 + (size_t)NBLKS*128*256,    // [128][64]         Wenc^T
  HTOT_HALFS = HOFF_WE + 128*64
};

// ---- workspace layout (float offsets) ----
enum : size_t {
  WOFF_Y     = 0,                                    // __half [NROWS*DE] encoder out
  WOFF_H     = WOFF_Y + (size_t)NROWS*DE/2,          // __half [NROWS*DE] running hidden
  WOFF_W16   = WOFF_H + (size_t)NROWS*DE/2,          // f16 weights
  WOFF_LAM   = WOFF_W16 + (HTOT_HALFS+1)/2,          // [NBLK][256][2] f32
  WOFF_LAML  = WOFF_LAM + (size_t)NBLKS*HH*2,        // [NBLK][256][2] lam^32
  WOFF_SL    = WOFF_LAML + (size_t)NBLKS*HH*2,       // [B][128][256][2] chunk-local states
  WOFF_CARRY = WOFF_SL + (size_t)BB*NC32*HH*2,       // [B][128][256][2] chunk-start carries
  WOFF_STATS = WOFF_CARRY + (size_t)BB*NC32*HH*2,    // [NBLK+1][2][128]
  WOFF_POOL  = WOFF_STATS + (size_t)(NBLKS+1)*2*DE,  // [B][128]
  WOFF_BU    = WOFF_POOL + (size_t)BB*DE,            // __half [B][128][512][32]
  WS_FLOATS  = WOFF_BU + (size_t)BB*NC32*512*32/2
};

// ============================ prep ============================
__global__ __launch_bounds__(256) void k_prep(
    const float* __restrict__ nu_log, const float* __restrict__ theta_log,
    const float* __restrict__ B_re, const float* __restrict__ B_im,
    const float* __restrict__ C_re, const float* __restrict__ C_im,
    const float* __restrict__ W1g, const float* __restrict__ W2g,
    const float* __restrict__ Wenc, float* __restrict__ ws)
{
  const int i = blockIdx.x, h = threadIdx.x;
  __half* w16 = (__half*)(ws + WOFF_W16);
  const float nu  = expf(nu_log[i*HH+h]);
  const float th  = expf(theta_log[i*HH+h]);
  const float mod = expf(-nu);
  const float lr = mod*cosf(th), li = mod*sinf(th);
  const float gamma = sqrtf(fmaxf(1.0f - mod*mod, 1e-8f));
  ws[WOFF_LAM + ((size_t)i*HH+h)*2+0] = lr;
  ws[WOFF_LAM + ((size_t)i*HH+h)*2+1] = li;
  {
    float ar = lr, ai = li;
    #pragma unroll
    for (int q = 0; q < 5; q++) { float nr=ar*ar-ai*ai, ni=2.0f*ar*ai; ar=nr; ai=ni; }
    ws[WOFF_LAML + ((size_t)i*HH+h)*2+0] = ar;   // lam^32
    ws[WOFF_LAML + ((size_t)i*HH+h)*2+1] = ai;
  }
  // BG [512][128]
  {
    __half* bg = w16 + HOFF_BG + (size_t)i*512*128;
    const float* bre = B_re + ((size_t)i*HH+h)*DE;
    const float* bim = B_im + ((size_t)i*HH+h)*DE;
    for (int d = 0; d < DE; d++) {
      bg[(size_t)h*128 + d]       = __float2half(bre[d]*gamma);
      bg[(size_t)(256+h)*128 + d] = __float2half(bim[d]*gamma);
    }
  }
  // WC [128][512]
  {
    __half* wc = w16 + HOFF_WC + (size_t)i*128*512;
    const float* cre = C_re + (size_t)i*DE*HH;
    const float* cim = C_im + (size_t)i*DE*HH;
    for (int d = 0; d < DE; d++) {
      wc[(size_t)d*512 + h]       = __float2half( cre[(size_t)d*HH + h]);
      wc[(size_t)d*512 + 256 + h] = __float2half(-cim[(size_t)d*HH + h]);
    }
  }
  // W1T [512][128]
  {
    __half* w1t = w16 + HOFF_W1 + (size_t)i*512*128;
    for (int d = 0; d < DE; d++) {
      w1t[(size_t)h*128 + d]       = __float2half(W1g[((size_t)i*DE + d)*LDIM + h]);
      w1t[(size_t)(256+h)*128 + d] = __float2half(W1g[((size_t)i*DE + d)*LDIM + 256 + h]);
    }
  }
  // W2T [128][256]
  if (h < 128) {
    __half* w2t = w16 + HOFF_W2 + (size_t)i*128*256;
    for (int g = 0; g < 256; g++)
      w2t[(size_t)h*256 + g] = __float2half(W2g[((size_t)i*256 + g)*DE + h]);
  }
  // WencT [128][64]
  if (i == 0 && h < 128) {
    __half* wet = w16 + HOFF_WE;
    for (int k = 0; k < TSZ; k++)
      wet[(size_t)h*TSZ + k] = __float2half(Wenc[(size_t)k*DE + h]);
  }
}

// ============================ encoder ============================
__global__ __launch_bounds__(512) void k_enc(
    const float* __restrict__ x, const float* __restrict__ benc, float* __restrict__ ws)
{
  __shared__ __half XT[64*72];
  const int tid = threadIdx.x, w = tid >> 6, l = tid & 63;
  const size_t row0 = (size_t)blockIdx.x * 64;
  {
    const float4* xg = (const float4*)(x + row0*TSZ);
    for (int idx = tid; idx < 1024; idx += 512) {
      float4 v = xg[idx];
      const int r = idx >> 4, c4 = (idx & 15)*4;
      *(__half2*)&XT[r*72 + c4]     = __half2{__float2half(v.x), __float2half(v.y)};
      *(__half2*)&XT[r*72 + c4 + 2] = __half2{__float2half(v.z), __float2half(v.w)};
    }
  }
  __syncthreads();
  const __half* wet = (const __half*)(ws + WOFF_W16) + HOFF_WE;
  const int n0 = w*16;
  f32x4 acc[4];
  #pragma unroll
  for (int mt = 0; mt < 4; mt++) acc[mt] = (f32x4)(0.0f);
  #pragma unroll
  for (int k0 = 0; k0 < 64; k0 += 32) {
    f16x8 bf = *(const f16x8*)&wet[(size_t)(n0 + (l&15))*64 + k0 + (l>>4)*8];
    #pragma unroll
    for (int mt = 0; mt < 4; mt++) {
      f16x8 af = *(const f16x8*)&XT[(mt*16 + (l&15))*72 + k0 + (l>>4)*8];
      acc[mt] = MFMA16(af, bf, acc[mt]);
    }
  }
  const int d = n0 + (l&15);
  const float be = benc[d];
  float s = 0.0f, ss = 0.0f;
  __half* y = (__half*)(ws + WOFF_Y);
  #pragma unroll
  for (int mt = 0; mt < 4; mt++)
    #pragma unroll
    for (int j = 0; j < 4; j++) {
      const int t = mt*16 + (l>>4)*4 + j;
      const float v = acc[mt][j] + be;
      y[(row0 + t)*DE + d] = __float2half(v);
      s += v; ss += v*v;
    }
  s  += __shfl_xor(s, 16);  s  += __shfl_xor(s, 32);
  ss += __shfl_xor(ss, 16); ss += __shfl_xor(ss, 32);
  if (l < 16) {
    atomicAdd(ws + WOFF_STATS + d, s);
    atomicAdd(ws + WOFF_STATS + DE + d, ss);
  }
}

// ============================ k_A: BN + B-proj -> Bu ============================
__global__ __launch_bounds__(512, 4) void k_A(
    const __half* __restrict__ hin, float* __restrict__ ws,
    const float* __restrict__ bnsg, const float* __restrict__ bnbg, int iblk)
{
  __shared__ float AC[256];
  __shared__ __half U[64*136];
  const int tid = threadIdx.x, w = tid >> 6, l = tid & 63, q = l >> 4, r = l & 15;
  const int b = blockIdx.y, cb = blockIdx.x;
  const int row0 = b*TT + cb*64;
  if (tid < 128) {
    const float inv = 1.0f / (float)NROWS;
    const float s  = ws[WOFF_STATS + ((size_t)iblk*2+0)*DE + tid];
    const float sq = ws[WOFF_STATS + ((size_t)iblk*2+1)*DE + tid];
    const float mean = s*inv;
    const float var  = sq*inv - mean*mean;
    const float a = rsqrtf(var + EPSF) * bnsg[iblk*DE + tid];
    AC[tid]       = a;
    AC[128 + tid] = bnbg[iblk*DE + tid] - mean*a;
  }
  __syncthreads();
  {
    const int row = tid >> 3, d0 = (tid & 7)*16;
    const f16x8* hp = (const f16x8*)(hin + (size_t)(row0+row)*DE + d0);
    f16x8 h0 = hp[0], h1 = hp[1];
    f16x8 u0, u1;
    #pragma unroll
    for (int j = 0; j < 8; j++) {
      u0[j] = (_Float16)((float)h0[j]*AC[d0+j]   + AC[128+d0+j]);
      u1[j] = (_Float16)((float)h1[j]*AC[d0+8+j] + AC[128+d0+8+j]);
    }
    *(f16x8*)&U[row*136 + d0]     = u0;
    *(f16x8*)&U[row*136 + d0 + 8] = u1;
  }
  __syncthreads();
  const __half* BG = (const __half*)(ws + WOFF_W16) + HOFF_BG + (size_t)iblk*512*128;
  const int n0 = w*64;
  f32x4 acc[4][4];
  #pragma unroll
  for (int mt = 0; mt < 4; mt++)
    #pragma unroll
    for (int nt = 0; nt < 4; nt++) acc[mt][nt] = (f32x4)(0.0f);
  #pragma unroll
  for (int k0 = 0; k0 < 128; k0 += 32) {
    f16x8 af[4], bf[4];
    #pragma unroll
    for (int mt = 0; mt < 4; mt++)
      af[mt] = *(const f16x8*)&U[(mt*16 + r)*136 + k0 + q*8];
    #pragma unroll
    for (int nt = 0; nt < 4; nt++)
      bf[nt] = *(const f16x8*)&BG[(size_t)(n0 + nt*16 + r)*128 + k0 + q*8];
    #pragma unroll
    for (int mt = 0; mt < 4; mt++)
      #pragma unroll
      for (int nt = 0; nt < 4; nt++)
        acc[mt][nt] = MFMA16(af[mt], bf[nt], acc[mt][nt]);
  }
  // Bu [b][c32][hc][t32]
  __half* bu = (__half*)(ws + WOFF_BU);
  #pragma unroll
  for (int mt = 0; mt < 4; mt++)
    #pragma unroll
    for (int nt = 0; nt < 4; nt++) {
      f16x4 pk;
      pk[0] = (_Float16)acc[mt][nt][0];
      pk[1] = (_Float16)acc[mt][nt][1];
      pk[2] = (_Float16)acc[mt][nt][2];
      pk[3] = (_Float16)acc[mt][nt][3];
      const int hc = n0 + nt*16 + r;
      __half* dst = bu + ((((size_t)b*NC32 + cb*2 + (mt>>1))*512 + hc)*32 + (mt&1)*16 + q*4);
      *(f16x4*)dst = pk;
    }
}

// ============================ k_pre: local scans -> SL ============================
__global__ __launch_bounds__(256) void k_pre(float* __restrict__ ws, int iblk)
{
  const int h = threadIdx.x, c = blockIdx.x, b = blockIdx.y;
  const __half* bu = (const __half*)(ws + WOFF_BU) + ((size_t)(b*NC32 + c)*512)*32;
  f16x8 re[4], im[4];
  #pragma unroll
  for (int k = 0; k < 4; k++) {
    re[k] = *(const f16x8*)(bu + (size_t)h*32 + k*8);
    im[k] = *(const f16x8*)(bu + (size_t)(256+h)*32 + k*8);
  }
  const float lr = ws[WOFF_LAM + ((size_t)iblk*HH+h)*2+0];
  const float li = ws[WOFF_LAM + ((size_t)iblk*HH+h)*2+1];
  float sr = 0.0f, si = 0.0f;
  #pragma unroll
  for (int t = 0; t < 32; t++) {
    const float br = (float)re[t>>3][t&7];
    const float bi = (float)im[t>>3][t&7];
    const float nr = lr*sr - li*si + br;
    const float ni = lr*si + li*sr + bi;
    sr = nr; si = ni;
  }
  ws[WOFF_SL + ((size_t)(b*NC32+c)*HH + h)*2+0] = sr;
  ws[WOFF_SL + ((size_t)(b*NC32+c)*HH + h)*2+1] = si;
}

// ============================ k_carry: serial O(NC) carry chain ============================
__global__ void k_carry(float* __restrict__ ws, int i)
{
  const int h = threadIdx.x;   // 256
  const int b = blockIdx.x;    // 16
  const float Lr = ws[WOFF_LAML + ((size_t)i*HH+h)*2+0];
  const float Li = ws[WOFF_LAML + ((size_t)i*HH+h)*2+1];
  float2* C = (float2*)(ws + WOFF_CARRY) + (size_t)b*NC32*HH + h;
  const float2* S = (const float2*)(ws + WOFF_SL) + (size_t)b*NC32*HH + h;
  float sr = 0.0f, si = 0.0f;
  C[0] = float2{0.0f, 0.0f};
  for (int c = 1; c < NC32; c++) {
    const float2 sl = S[(size_t)(c-1)*HH];
    const float nr = Lr*sr - Li*si + sl.x;
    const float ni = Lr*si + Li*sr + sl.y;
    sr = nr; si = ni;
    C[(size_t)c*HH] = float2{sr, si};
  }
}

// ============================ k_BC: scan + C-proj + MLP (64-row tiles) ============================
__global__ __launch_bounds__(512, 4) void k_BC(
    const __half* __restrict__ hin, float* __restrict__ ws,
    const float* __restrict__ bnsg, const float* __restrict__ bnbg,
    const float* __restrict__ b1g, const float* __restrict__ b2g,
    const float* __restrict__ Dvg, int iblk, int islast)
{
  __shared__ __half HT[64*264];   // sr-half -> si-half -> G (overlaid)
  __shared__ __half YL[64*136];
  __shared__ float AC[256];
  __shared__ float DVs[128];
  const int tid = threadIdx.x, w = tid >> 6, l = tid & 63, q = l >> 4, r = l & 15;
  const int b = blockIdx.y, cb = blockIdx.x;
  const int row0 = b*TT + cb*64;
  const __half* w16 = (const __half*)(ws + WOFF_W16);

  if (tid < 128) {
    const float inv = 1.0f / (float)NROWS;
    const float s  = ws[WOFF_STATS + ((size_t)iblk*2+0)*DE + tid];
    const float sq = ws[WOFF_STATS + ((size_t)iblk*2+1)*DE + tid];
    const float mean = s*inv;
    const float var  = sq*inv - mean*mean;
    const float a = rsqrtf(var + EPSF) * bnsg[iblk*DE + tid];
    AC[tid]       = a;
    AC[128 + tid] = bnbg[iblk*DE + tid] - mean*a;
    DVs[tid] = Dvg[iblk*DE + tid];
  }

  // ---- S1: scan. thread = (channel h, t-half p); 32-step register scan ----
  __half2 simv[16];
  {
    const int h = tid & 255, p = tid >> 8;
    const int c32 = cb*2 + p;
    const float2 carry = *((const float2*)(ws + WOFF_CARRY) + ((size_t)b*NC32 + c32)*HH + h);
    const __half* bu = (const __half*)(ws + WOFF_BU) + ((size_t)(b*NC32 + c32)*512)*32;
    f16x8 re[4], im[4];
    #pragma unroll
    for (int k = 0; k < 4; k++) {
      re[k] = *(const f16x8*)(bu + (size_t)h*32 + k*8);
      im[k] = *(const f16x8*)(bu + (size_t)(256+h)*32 + k*8);
    }
    const float lr = ws[WOFF_LAM + ((size_t)iblk*HH+h)*2+0];
    const float li = ws[WOFF_LAM + ((size_t)iblk*HH+h)*2+1];
    float sr = carry.x, si = carry.y;
    #pragma unroll
    for (int t = 0; t < 32; t++) {
      const float br = (float)re[t>>3][t&7];
      const float bi = (float)im[t>>3][t&7];
      const float nr = lr*sr - li*si + br;
      const float ni = lr*si + li*sr + bi;
      sr = nr; si = ni;
      HT[(p*32 + t)*264 + h] = __float2half(sr);
      if ((t & 1) == 0) simv[t>>1].x = __float2half(si);
      else              simv[t>>1].y = __float2half(si);
    }
  }
  __syncthreads();

  // ---- S2a: C-proj over re-half (K=256) ----
  const __half* WC = w16 + HOFF_WC + (size_t)iblk*128*512;
  const int d = w*16 + r;
  f32x4 acc2[4];
  #pragma unroll
  for (int mt = 0; mt < 4; mt++) acc2[mt] = (f32x4)(0.0f);
  #pragma unroll
  for (int k0 = 0; k0 < 256; k0 += 32) {
    f16x8 bf = *(const f16x8*)&WC[(size_t)d*512 + k0 + q*8];
    #pragma unroll
    for (int mt = 0; mt < 4; mt++) {
      f16x8 af = *(const f16x8*)&HT[(mt*16 + r)*264 + k0 + q*8];
      acc2[mt] = MFMA16(af, bf, acc2[mt]);
    }
  }
  __syncthreads();
  // ---- swap in si-half ----
  {
    const int h = tid & 255, p = tid >> 8;
    #pragma unroll
    for (int t = 0; t < 32; t++)
      HT[(p*32 + t)*264 + h] = ((t & 1) ? simv[t>>1].y : simv[t>>1].x);
  }
  __syncthreads();
  // ---- S2b: C-proj over im-half (K=256) + u*D -> YL ----
  #pragma unroll
  for (int k0 = 0; k0 < 256; k0 += 32) {
    f16x8 bf = *(const f16x8*)&WC[(size_t)d*512 + 256 + k0 + q*8];
    #pragma unroll
    for (int mt = 0; mt < 4; mt++) {
      f16x8 af = *(const f16x8*)&HT[(mt*16 + r)*264 + k0 + q*8];
      acc2[mt] = MFMA16(af, bf, acc2[mt]);
    }
  }
  {
    const float dv = DVs[d], a = AC[d], c = AC[128+d];
    #pragma unroll
    for (int mt = 0; mt < 4; mt++)
      #pragma unroll
      for (int j = 0; j < 4; j++) {
        const int t = mt*16 + q*4 + j;
        const float u = (float)hin[(size_t)(row0+t)*DE + d]*a + c;
        YL[t*136 + d] = __float2half(acc2[mt][j] + u*dv);
      }
  }
  __syncthreads();

  // ---- S3: W1 + GLU -> G (overlays HT). Wave: paired cols (ca, 256+ca) ----
  {
    const __half* W1T = w16 + HOFF_W1 + (size_t)iblk*512*128;
    #pragma unroll
    for (int nt = 0; nt < 2; nt++) {
      const int ca = w*32 + nt*16 + r;
      f32x4 aa[4], ab[4];
      #pragma unroll
      for (int mt = 0; mt < 4; mt++) { aa[mt] = (f32x4)(0.0f); ab[mt] = (f32x4)(0.0f); }
      #pragma unroll
      for (int k0 = 0; k0 < 128; k0 += 32) {
        f16x8 ba = *(const f16x8*)&W1T[(size_t)ca*128 + k0 + q*8];
        f16x8 bb = *(const f16x8*)&W1T[(size_t)(256+ca)*128 + k0 + q*8];
        #pragma unroll
        for (int mt = 0; mt < 4; mt++) {
          f16x8 af = *(const f16x8*)&YL[(mt*16 + r)*136 + k0 + q*8];
          aa[mt] = MFMA16(af, ba, aa[mt]);
          ab[mt] = MFMA16(af, bb, ab[mt]);
        }
      }
      const float b1a = b1g[(size_t)iblk*LDIM + ca];
      const float b1b = b1g[(size_t)iblk*LDIM + 256 + ca];
      #pragma unroll
      for (int mt = 0; mt < 4; mt++)
        #pragma unroll
        for (int j = 0; j < 4; j++) {
          const int t = mt*16 + q*4 + j;
          const float av = aa[mt][j] + b1a;
          const float bv = ab[mt][j] + b1b;
          HT[t*264 + ca] = __float2half(av / (1.0f + __expf(-bv)));
        }
    }
  }
  __syncthreads();

  // ---- S4: h' = G @ W2 + b2 + y ----
  {
    const __half* W2T = w16 + HOFF_W2 + (size_t)iblk*128*256;
    f32x4 ac4[4];
    #pragma unroll
    for (int mt = 0; mt < 4; mt++) ac4[mt] = (f32x4)(0.0f);
    #pragma unroll
    for (int k0 = 0; k0 < 256; k0 += 32) {
      f16x8 bf = *(const f16x8*)&W2T[(size_t)d*256 + k0 + q*8];
      #pragma unroll
      for (int mt = 0; mt < 4; mt++) {
        f16x8 af = *(const f16x8*)&HT[(mt*16 + r)*264 + k0 + q*8];
        ac4[mt] = MFMA16(af, bf, ac4[mt]);
      }
    }
    const __half* yh = (const __half*)(ws + WOFF_Y);
    __half* hh = (__half*)(ws + WOFF_H);
    const float bb2 = b2g[(size_t)iblk*DE + d];
    float s = 0.0f, ss = 0.0f;
    #pragma unroll
    for (int mt = 0; mt < 4; mt++)
      #pragma unroll
      for (int j = 0; j < 4; j++) {
        const int t = mt*16 + q*4 + j;
        const size_t row = (size_t)(row0 + t);
        const float v = ac4[mt][j] + bb2 + (float)yh[row*DE + d];
        hh[row*DE + d] = __float2half(v);
        s += v; ss += v*v;
      }
    s  += __shfl_xor(s, 16);  s  += __shfl_xor(s, 32);
    ss += __shfl_xor(ss, 16); ss += __shfl_xor(ss, 32);
    if (l < 16) {
      atomicAdd(ws + WOFF_STATS + (size_t)((iblk+1)*2 + 0)*DE + d, s);
      atomicAdd(ws + WOFF_STATS + (size_t)((iblk+1)*2 + 1)*DE + d, ss);
      if (islast) atomicAdd(ws + WOFF_POOL + (size_t)b*DE + d, s);
    }
  }
}

// ============================ final projection ============================
__global__ void k_out(const float* __restrict__ Wout, const float* __restrict__ bout,
                      const float* __restrict__ ws, float* __restrict__ out)
{
  const int tid = threadIdx.x;
  if (tid < BB*ODIM) {
    const int b = tid / ODIM, o = tid % ODIM;
    float acc = bout[o];
    const float* p = ws + WOFF_POOL + (size_t)b*DE;
    const float invT = 1.0f / (float)TT;
    for (int d = 0; d < DE; d++) acc += p[d]*invT*Wout[d*ODIM + o];
    out[tid] = acc;
  }
}

extern "C" void kernel_launch(void* const* d_in, const int* in_sizes, int n_in,
                              void* d_out, int out_size, void* d_ws, size_t ws_size,
                              hipStream_t stream)
{
  const float* x   = (const float*)d_in[0];
  const float* nu  = (const float*)d_in[1];
  const float* th  = (const float*)d_in[2];
  const float* Bre = (const float*)d_in[3];
  const float* Bim = (const float*)d_in[4];
  const float* Cre = (const float*)d_in[5];
  const float* Cim = (const float*)d_in[6];
  const float* Dv  = (const float*)d_in[7];
  const float* W1  = (const float*)d_in[8];
  const float* b1  = (const float*)d_in[9];
  const float* W2  = (const float*)d_in[10];
  const float* b2  = (const float*)d_in[11];
  const float* bns = (const float*)d_in[12];
  const float* bnb = (const float*)d_in[13];
  const float* We  = (const float*)d_in[14];
  const float* be  = (const float*)d_in[15];
  const float* Wo  = (const float*)d_in[16];
  const float* bo  = (const float*)d_in[17];
  float* ws = (float*)d_ws;
  float* out = (float*)d_out;

  hipMemsetAsync(ws + WOFF_STATS, 0,
                 (size_t)(((NBLKS+1)*2*DE) + BB*DE)*sizeof(float), stream);

  k_prep<<<NBLKS, 256, 0, stream>>>(nu, th, Bre, Bim, Cre, Cim, W1, W2, We, ws);
  k_enc<<<NROWS/64, 512, 0, stream>>>(x, be, ws);

  const __half* Yh = (const __half*)(ws + WOFF_Y);
  const __half* Hh = (const __half*)(ws + WOFF_H);
  for (int i = 0; i < NBLKS; i++) {
    const __half* hin = (i == 0) ? Yh : Hh;
    k_A    <<<dim3(NC64, BB), 512, 0, stream>>>(hin, ws, bns, bnb, i);
    k_pre  <<<dim3(NC32, BB), 256, 0, stream>>>(ws, i);
    k_carry<<<BB, 256, 0, stream>>>(ws, i);
    k_BC   <<<dim3(NC64, BB), 512, 0, stream>>>(hin, ws, bns, bnb, b1, b2, Dv, i,
                                                (i == NBLKS-1) ? 1 : 0);
  }
  k_out<<<1, 256, 0, stream>>>(Wo, bo, ws, out);
}